// Round 8
// baseline (231.263 us; speedup 1.0000x reference)
//
#include <hip/hip_runtime.h>

#define NPOS   65536      // 16*16*16*16 positions
#define CDIM   256
#define KCODES 512
#define ZTOT   16777216   // 16*256*16*16*16
#define IDX_OFF (ZTOT + 1)
#define TAU    2.0e-3f
#define GL_CAP 16384

// ws layout (float idx): [0]=loss acc; int[1]=refine count; [64..576)=cb_sq f32;
// [66112..131648) = cb bf16 in MFMA-fragment order (ushort[131072]);
// int[132096..) = candidate slots: 10 ints each {n, nc, cand[8]}, GL_CAP slots
#define WS_CBSQ 64
#define WS_CBBF 66112
#define WS_GLI  132096
#define NC_FULL 0x7fff

using bf16x8 = __attribute__((ext_vector_type(8))) short;
using f32x4  = __attribute__((ext_vector_type(4))) float;

__device__ __forceinline__ unsigned short f2bf(float f) {
    unsigned int u = __float_as_uint(f);
    return (unsigned short)((u + 0x7fffu + ((u >> 16) & 1u)) >> 16);
}

// numpy pairwise sum-of-squares, f32, contraction-proof (verified r3)
__device__ __forceinline__ float np_pw128_sq(const float* a) {
    float r[8];
    #pragma unroll
    for (int j = 0; j < 8; ++j) r[j] = __fmul_rn(a[j], a[j]);
    #pragma unroll 1
    for (int i = 8; i < 128; i += 8) {
        #pragma unroll
        for (int j = 0; j < 8; ++j)
            r[j] = __fadd_rn(r[j], __fmul_rn(a[i + j], a[i + j]));
    }
    return __fadd_rn(__fadd_rn(__fadd_rn(r[0], r[1]), __fadd_rn(r[2], r[3])),
                     __fadd_rn(__fadd_rn(r[4], r[5]), __fadd_rn(r[6], r[7])));
}

__global__ void vq_prep(const float* __restrict__ cb, float* __restrict__ ws) {
    int k = threadIdx.x;            // 512 threads, 1 block
    if (k == 0) { ws[0] = 0.0f; ((int*)ws)[1] = 0; }
    const float* row = cb + k * CDIM;
    ws[WS_CBSQ + k] = __fadd_rn(np_pw128_sq(row), np_pw128_sq(row + 128));
}

// bf16 codebook pre-permuted into MFMA fragment order:
// dest[((nt_g*8 + kt)*64 + g*16 + c0)*8 + j]  <-  cb[k][c]
// where nt_g=k>>4, c0=k&15, kt=c>>5, g=(c&31)>>3, j=c&7.
// Screen's B load for (w,nt,kt,lane l) is then 64x16B CONTIGUOUS (1 KB).
__global__ void vq_cvt(const float* __restrict__ cb, float* __restrict__ ws) {
    unsigned short* cbf2 = (unsigned short*)(ws + WS_CBBF);
    const int i = blockIdx.x * 256 + threadIdx.x;   // 512 blocks x 256
    const int k = i >> 8, c = i & 255;
    const int nt_g = k >> 4, c0 = k & 15;
    const int kt = c >> 5, g = (c & 31) >> 3, j = c & 7;
    cbf2[(((nt_g * 8 + kt) * 64) + g * 16 + c0) * 8 + j] = f2bf(cb[i]);
}

// Screening: s[k] = cbsq[k] - 2*dot_bf16 (MFMA). Block = 32 rows x 512 codes,
// 4 waves split codes. A staged in LDS fragment order; A-frags re-read from
// LDS per nt (keeps regs <=128 for 4 blocks/CU). Scores bit-identical to r7.
__launch_bounds__(256, 4)
__global__ void vq_screen(const float* __restrict__ z,
                          float* __restrict__ ws,
                          float* __restrict__ out) {
    const int t  = threadIdx.x;
    const int w  = t >> 6;          // wave id: codes [w*128, w*128+128)
    const int l  = t & 63;
    const int g  = l >> 4;
    const int c0 = l & 15;
    const int m0 = blockIdx.x * 32;
    const int b  = m0 >> 12;
    const int s0 = m0 & 4095;
    const float* zb = z + (size_t)b * 1048576 + s0;
    const unsigned short* cbf2 = (const unsigned short*)(ws + WS_CBBF);
    int* wsi = (int*)ws;

    // A tile in MFMA fragment order: [kt][mt][lane][8 bf16] = 16 KB
    __shared__ unsigned short ldsA[8][2][64][8];
    __shared__ float cbsq_s[KCODES];
    __shared__ float red[4 * 32 * 2];    // [w][row][v1,i1]
    __shared__ float fv1[32];
    __shared__ int   ccnt[32];
    __shared__ int   cand[32][8];

    cbsq_s[t]       = ws[WS_CBSQ + t];
    cbsq_s[256 + t] = ws[WS_CBSQ + 256 + t];
    if (t < 32) ccnt[t] = 0;

    // ---- stage A: coalesced float4 z loads -> bf16 -> fragment-order LDS ----
    {
        const int cb8 = t >> 3;         // channel within pass-group of 32
        const int s4  = t & 7;          // position quad
        #pragma unroll
        for (int pass = 0; pass < 8; ++pass) {
            const int c  = pass * 32 + cb8;
            const int kt = c >> 5, ko = c & 31, gg = ko >> 3, j = ko & 7;
            float4 v = *(const float4*)(zb + (size_t)c * 4096 + s4 * 4);
            const int p0 = s4 * 4;
            ldsA[kt][(p0 + 0) >> 4][gg * 16 + ((p0 + 0) & 15)][j] = f2bf(v.x);
            ldsA[kt][(p0 + 1) >> 4][gg * 16 + ((p0 + 1) & 15)][j] = f2bf(v.y);
            ldsA[kt][(p0 + 2) >> 4][gg * 16 + ((p0 + 2) & 15)][j] = f2bf(v.z);
            ldsA[kt][(p0 + 3) >> 4][gg * 16 + ((p0 + 3) & 15)][j] = f2bf(v.w);
        }
    }
    __syncthreads();

    f32x4 acc[2][8];
    #pragma unroll
    for (int mt = 0; mt < 2; ++mt)
        #pragma unroll
        for (int nt = 0; nt < 8; ++nt)
            acc[mt][nt] = (f32x4){0.f, 0.f, 0.f, 0.f};

    #pragma unroll 2
    for (int nt = 0; nt < 8; ++nt) {
        // contiguous 1 KB per (nt,kt): lanes l*16B
        const unsigned short* bp = cbf2 + (((size_t)(w * 8 + nt) * 8) << 9) + (l << 3);
        #pragma unroll
        for (int kt = 0; kt < 8; ++kt) {
            const bf16x8 bfr = *(const bf16x8*)(bp + (kt << 9));
            const bf16x8 a0 = *(const bf16x8*)&ldsA[kt][0][l][0];
            const bf16x8 a1 = *(const bf16x8*)&ldsA[kt][1][l][0];
            acc[0][nt] = __builtin_amdgcn_mfma_f32_16x16x32_bf16(a0, bfr, acc[0][nt], 0, 0, 0);
            acc[1][nt] = __builtin_amdgcn_mfma_f32_16x16x32_bf16(a1, bfr, acc[1][nt], 0, 0, 0);
        }
    }

    __syncthreads();

    // per-lane argmin per row, merge across 16-lane col group
    #pragma unroll
    for (int mt = 0; mt < 2; ++mt) {
        #pragma unroll
        for (int reg = 0; reg < 4; ++reg) {
            const int row = mt * 16 + g * 4 + reg;
            float v1 = 3.4028235e38f;
            int   i1 = 0x7fffffff;
            #pragma unroll
            for (int nt = 0; nt < 8; ++nt) {
                const int k = w * 128 + nt * 16 + c0;
                const float s = fmaf(-2.0f, acc[mt][nt][reg], cbsq_s[k]);
                if (s < v1 || (s == v1 && k < i1)) { v1 = s; i1 = k; }
            }
            #pragma unroll
            for (int m = 1; m < 16; m <<= 1) {
                float pv1 = __shfl_xor(v1, m, 64);
                int   pi1 = __shfl_xor(i1, m, 64);
                if (pv1 < v1 || (pv1 == v1 && pi1 < i1)) { v1 = pv1; i1 = pi1; }
            }
            if (c0 == 0) {
                red[(w * 32 + row) * 2 + 0] = v1;
                red[(w * 32 + row) * 2 + 1] = __int_as_float(i1);
            }
        }
    }
    __syncthreads();

    if (t < 32) {
        float v1 = red[(0 * 32 + t) * 2 + 0];
        int   i1 = __float_as_int(red[(0 * 32 + t) * 2 + 1]);
        #pragma unroll
        for (int ww = 1; ww < 4; ++ww) {
            float pv1 = red[(ww * 32 + t) * 2 + 0];
            int   pi1 = __float_as_int(red[(ww * 32 + t) * 2 + 1]);
            if (pv1 < v1 || (pv1 == v1 && pi1 < i1)) { v1 = pv1; i1 = pi1; }
        }
        out[IDX_OFF + m0 + t] = (float)i1;   // provisional (final unless refined)
        fv1[t] = v1;
    }
    __syncthreads();

    // candidate scan: every code within TAU of the row min
    #pragma unroll
    for (int mt = 0; mt < 2; ++mt) {
        #pragma unroll
        for (int reg = 0; reg < 4; ++reg) {
            const int row = mt * 16 + g * 4 + reg;
            const float lim = fv1[row] + TAU;
            #pragma unroll
            for (int nt = 0; nt < 8; ++nt) {
                const int k = w * 128 + nt * 16 + c0;
                const float s = fmaf(-2.0f, acc[mt][nt][reg], cbsq_s[k]);
                if (s < lim) {
                    int pos = atomicAdd(&ccnt[row], 1);
                    if (pos < 8) cand[row][pos] = k;
                }
            }
        }
    }
    __syncthreads();

    if (t < 32) {
        const int nc = ccnt[t];
        if (nc > 1) {
            int slot = atomicAdd(wsi + 1, 1);
            if (slot < GL_CAP) {
                int* gl = wsi + WS_GLI + slot * 10;
                gl[0] = m0 + t;
                gl[1] = (nc > 8) ? NC_FULL : nc;
                #pragma unroll
                for (int q = 0; q < 8; ++q)
                    gl[2 + q] = (q < nc && q < 8) ? cand[t][q] : 0;
            }
        }
    }
}

// Exact np-replica on candidate codes only. One block per flagged row. (r6)
__global__ void vq_refine(const float* __restrict__ z,
                          const float* __restrict__ cb,
                          float* __restrict__ ws,
                          float* __restrict__ out) {
    int* wsi = (int*)ws;
    const int cnt = min(wsi[1], GL_CAP);
    const int t   = threadIdx.x;
    const int wid = t >> 6;
    const int l   = t & 63;

    __shared__ __align__(16) float zs[260];
    __shared__ float chres[16];
    __shared__ float zsq_sh;
    __shared__ float wbv[4];
    __shared__ int   wbi[4];

    for (int slot = blockIdx.x; slot < cnt; slot += gridDim.x) {
        __syncthreads();
        const int* gl = wsi + WS_GLI + slot * 10;
        const int n  = gl[0];
        const int nc = gl[1];
        const size_t zb = (size_t)(n >> 12) * 1048576 + (size_t)(n & 4095);
        zs[t] = z[zb + (size_t)t * 4096];
        __syncthreads();

        if (t < 16) {
            const float* a = &zs[(t & 8) * 16];
            const int j = t & 7;
            float r = __fmul_rn(a[j], a[j]);
            #pragma unroll 1
            for (int m = 1; m < 16; ++m)
                r = __fadd_rn(r, __fmul_rn(a[j + 8 * m], a[j + 8 * m]));
            chres[t] = r;
        }
        __syncthreads();
        if (t == 0) {
            float h0 = __fadd_rn(__fadd_rn(__fadd_rn(chres[0], chres[1]), __fadd_rn(chres[2], chres[3])),
                                 __fadd_rn(__fadd_rn(chres[4], chres[5]), __fadd_rn(chres[6], chres[7])));
            float h1 = __fadd_rn(__fadd_rn(__fadd_rn(chres[8], chres[9]), __fadd_rn(chres[10], chres[11])),
                                 __fadd_rn(__fadd_rn(chres[12], chres[13]), __fadd_rn(chres[14], chres[15])));
            zsq_sh = __fadd_rn(h0, h1);
        }
        __syncthreads();
        const float zsq = zsq_sh;
        const float4 zl = *(const float4*)&zs[4 * l];

        float bv = 3.4028235e38f;
        int   bi = 0x7fffffff;
        if (nc != NC_FULL) {
            for (int ci = wid; ci < nc; ci += 4) {
                const int k = gl[2 + ci];
                const float4 e = *(const float4*)(cb + (size_t)k * CDIM + 4 * l);
                double d = (double)e.x * (double)zl.x + (double)e.y * (double)zl.y
                         + (double)e.z * (double)zl.z + (double)e.w * (double)zl.w;
                #pragma unroll
                for (int m = 1; m < 64; m <<= 1)
                    d += __shfl_xor(d, m, 64);
                const float dist = __fsub_rn(__fadd_rn(zsq, ws[WS_CBSQ + k]),
                                             __fmul_rn(2.0f, (float)d));
                if (dist < bv || (dist == bv && k < bi)) { bv = dist; bi = k; }
            }
        } else {
            for (int k = wid; k < KCODES; k += 4) {
                const float4 e = *(const float4*)(cb + (size_t)k * CDIM + 4 * l);
                double d = (double)e.x * (double)zl.x + (double)e.y * (double)zl.y
                         + (double)e.z * (double)zl.z + (double)e.w * (double)zl.w;
                #pragma unroll
                for (int m = 1; m < 64; m <<= 1)
                    d += __shfl_xor(d, m, 64);
                const float dist = __fsub_rn(__fadd_rn(zsq, ws[WS_CBSQ + k]),
                                             __fmul_rn(2.0f, (float)d));
                if (dist < bv || (dist == bv && k < bi)) { bv = dist; bi = k; }
            }
        }
        if (l == 0) { wbv[wid] = bv; wbi[wid] = bi; }
        __syncthreads();
        if (t == 0) {
            float v = wbv[0]; int i = wbi[0];
            #pragma unroll
            for (int ww = 1; ww < 4; ++ww) {
                if (wbv[ww] < v || (wbv[ww] == v && wbi[ww] < i)) { v = wbv[ww]; i = wbi[ww]; }
            }
            out[IDX_OFF + n] = (float)i;
        }
    }
}

// z_q gather + loss: block = 32 consecutive positions x 256 channels.
__launch_bounds__(256, 4)
__global__ void vq_gather(const float* __restrict__ z,
                          const float* __restrict__ cb,
                          float* __restrict__ out,
                          float* __restrict__ ws) {
    __shared__ int   sidx[32];
    __shared__ float lcb[32][257];
    const int t  = threadIdx.x;
    const int n0 = blockIdx.x * 32;
    const int b  = n0 >> 12;
    const int s0 = n0 & 4095;

    if (t < 32) sidx[t] = (int)out[IDX_OFF + n0 + t];
    __syncthreads();

    #pragma unroll 4
    for (int e = t; e < 32 * 256; e += 256) {
        const int r = e >> 8, c = e & 255;
        lcb[r][c] = cb[(size_t)sidx[r] * CDIM + c];
    }
    __syncthreads();

    float acc = 0.0f;
    const int sl = t & 31, cg = t >> 5;
    const size_t base = (size_t)b * 1048576 + (size_t)s0 + sl;
    #pragma unroll 4
    for (int i = 0; i < 32; ++i) {
        const int c = i * 8 + cg;
        const size_t o = base + (size_t)c * 4096;
        float v  = lcb[sl][c];
        float zv = z[o];
        out[o] = v;
        float df = v - zv;
        acc += df * df;
    }

    #pragma unroll
    for (int off = 32; off > 0; off >>= 1)
        acc += __shfl_down(acc, off, 64);
    __shared__ float wsum[4];
    const int lane = t & 63, wid = t >> 6;
    if (lane == 0) wsum[wid] = acc;
    __syncthreads();
    if (t == 0)
        atomicAdd(&ws[0], wsum[0] + wsum[1] + wsum[2] + wsum[3]);
}

__global__ void vq_fin(const float* __restrict__ ws, float* __restrict__ out) {
    if (threadIdx.x == 0)
        out[ZTOT] = 1.25f * ws[0] / (float)ZTOT;
}

extern "C" void kernel_launch(void* const* d_in, const int* in_sizes, int n_in,
                              void* d_out, int out_size, void* d_ws, size_t ws_size,
                              hipStream_t stream) {
    const float* z  = (const float*)d_in[0];
    const float* cb = (const float*)d_in[1];
    float* out = (float*)d_out;
    float* ws  = (float*)d_ws;

    vq_prep<<<1, 512, 0, stream>>>(cb, ws);
    vq_cvt<<<512, 256, 0, stream>>>(cb, ws);
    vq_screen<<<NPOS / 32, 256, 0, stream>>>(z, ws, out);
    vq_refine<<<2048, 256, 0, stream>>>(z, cb, ws, out);
    vq_gather<<<NPOS / 32, 256, 0, stream>>>(z, cb, out, ws);
    vq_fin<<<1, 64, 0, stream>>>(ws, out);
}

// Round 9
// 189.941 us; speedup vs baseline: 1.2176x; 1.2176x over previous
//
#include <hip/hip_runtime.h>

#define NPOS   65536      // 16*16*16*16 positions
#define CDIM   256
#define KCODES 512
#define ZTOT   16777216   // 16*256*16*16*16
#define IDX_OFF (ZTOT + 1)
#define TAU    2.0e-3f
#define GL_CAP 16384

// ws layout (float idx): [0]=loss acc; int[1]=refine count; [64..576)=cb_sq f32;
// [66112..131648) = cb bf16 in MFMA-fragment order (ushort[131072]);
// int[132096..) = candidate slots: 10 ints each {n, nc, cand[8]}, GL_CAP slots
#define WS_CBSQ 64
#define WS_CBBF 66112
#define WS_GLI  132096
#define NC_FULL 0x7fff

using bf16x8 = __attribute__((ext_vector_type(8))) short;
using f32x4  = __attribute__((ext_vector_type(4))) float;

__device__ __forceinline__ unsigned short f2bf(float f) {
    unsigned int u = __float_as_uint(f);
    return (unsigned short)((u + 0x7fffu + ((u >> 16) & 1u)) >> 16);
}

// numpy pairwise sum-of-squares, f32, contraction-proof (verified r3)
__device__ __forceinline__ float np_pw128_sq(const float* a) {
    float r[8];
    #pragma unroll
    for (int j = 0; j < 8; ++j) r[j] = __fmul_rn(a[j], a[j]);
    #pragma unroll 1
    for (int i = 8; i < 128; i += 8) {
        #pragma unroll
        for (int j = 0; j < 8; ++j)
            r[j] = __fadd_rn(r[j], __fmul_rn(a[i + j], a[i + j]));
    }
    return __fadd_rn(__fadd_rn(__fadd_rn(r[0], r[1]), __fadd_rn(r[2], r[3])),
                     __fadd_rn(__fadd_rn(r[4], r[5]), __fadd_rn(r[6], r[7])));
}

__global__ void vq_prep(const float* __restrict__ cb, float* __restrict__ ws) {
    int k = threadIdx.x;            // 512 threads, 1 block
    if (k == 0) { ws[0] = 0.0f; ((int*)ws)[1] = 0; }
    const float* row = cb + k * CDIM;
    ws[WS_CBSQ + k] = __fadd_rn(np_pw128_sq(row), np_pw128_sq(row + 128));
}

// bf16 codebook pre-permuted into MFMA fragment order (verified r8: identical
// absmax): dest[((nt_g*8 + kt)*64 + g*16 + c0)*8 + j] <- cb[k][c],
// nt_g=k>>4, c0=k&15, kt=c>>5, g=(c&31)>>3, j=c&7.
__global__ void vq_cvt(const float* __restrict__ cb, float* __restrict__ ws) {
    unsigned short* cbf2 = (unsigned short*)(ws + WS_CBBF);
    const int i = blockIdx.x * 256 + threadIdx.x;   // 512 blocks x 256
    const int k = i >> 8, c = i & 255;
    const int nt_g = k >> 4, c0 = k & 15;
    const int kt = c >> 5, g = (c & 31) >> 3, j = c & 7;
    cbf2[(((nt_g * 8 + kt) * 64) + g * 16 + c0) * 8 + j] = f2bf(cb[i]);
}

// Screening: s[k] = cbsq[k] - 2*dot_bf16 (MFMA). Block = 32 rows x 512 codes,
// 4 waves split codes. A staged via LDS into registers (once); contiguous
// fragment-order B with double-buffered prefetch. launch_bounds(256,2): DO NOT
// lower the register cap — r8's (256,4) spilled acc to scratch (263 MB writes).
__launch_bounds__(256, 2)
__global__ void vq_screen(const float* __restrict__ z,
                          float* __restrict__ ws,
                          float* __restrict__ out) {
    const int t  = threadIdx.x;
    const int w  = t >> 6;          // wave id: codes [w*128, w*128+128)
    const int l  = t & 63;
    const int g  = l >> 4;
    const int c0 = l & 15;
    const int m0 = blockIdx.x * 32;
    const int b  = m0 >> 12;
    const int s0 = m0 & 4095;
    const float* zb = z + (size_t)b * 1048576 + s0;
    const unsigned short* cbf2 = (const unsigned short*)(ws + WS_CBBF);
    int* wsi = (int*)ws;

    // A tile in MFMA fragment order: [kt][mt][lane][8 bf16] = 16 KB
    __shared__ unsigned short ldsA[8][2][64][8];
    __shared__ float cbsq_s[KCODES];
    __shared__ float red[4 * 32 * 2];    // [w][row][v1,i1]
    __shared__ float fv1[32];
    __shared__ int   ccnt[32];
    __shared__ int   cand[32][8];

    cbsq_s[t]       = ws[WS_CBSQ + t];
    cbsq_s[256 + t] = ws[WS_CBSQ + 256 + t];
    if (t < 32) ccnt[t] = 0;

    // ---- stage A: coalesced float4 z loads -> bf16 -> fragment-order LDS ----
    {
        const int cb8 = t >> 3;         // channel within pass-group of 32
        const int s4  = t & 7;          // position quad
        #pragma unroll
        for (int pass = 0; pass < 8; ++pass) {
            const int c  = pass * 32 + cb8;
            const int kt = c >> 5, ko = c & 31, gg = ko >> 3, j = ko & 7;
            float4 v = *(const float4*)(zb + (size_t)c * 4096 + s4 * 4);
            const int p0 = s4 * 4;
            ldsA[kt][(p0 + 0) >> 4][gg * 16 + ((p0 + 0) & 15)][j] = f2bf(v.x);
            ldsA[kt][(p0 + 1) >> 4][gg * 16 + ((p0 + 1) & 15)][j] = f2bf(v.y);
            ldsA[kt][(p0 + 2) >> 4][gg * 16 + ((p0 + 2) & 15)][j] = f2bf(v.z);
            ldsA[kt][(p0 + 3) >> 4][gg * 16 + ((p0 + 3) & 15)][j] = f2bf(v.w);
        }
    }
    __syncthreads();

    // ---- A fragments to registers (once) ----
    bf16x8 afr[2][8];
    #pragma unroll
    for (int kt = 0; kt < 8; ++kt) {
        afr[0][kt] = *(const bf16x8*)&ldsA[kt][0][l][0];
        afr[1][kt] = *(const bf16x8*)&ldsA[kt][1][l][0];
    }

    f32x4 acc[2][8];
    #pragma unroll
    for (int mt = 0; mt < 2; ++mt)
        #pragma unroll
        for (int nt = 0; nt < 8; ++nt)
            acc[mt][nt] = (f32x4){0.f, 0.f, 0.f, 0.f};

    // ---- MFMA loop: contiguous 1 KB B-blocks, double-buffered prefetch ----
    // element offset for (nt,kt): ((w*8+nt)*8 + kt)*512 + l*8
    bf16x8 bfr[2][8];
    {
        const unsigned short* bp0 = cbf2 + ((size_t)(w * 8 + 0) << 12) + (l << 3);
        #pragma unroll
        for (int kt = 0; kt < 8; ++kt)
            bfr[0][kt] = *(const bf16x8*)(bp0 + (kt << 9));
    }
    #pragma unroll
    for (int nt = 0; nt < 8; ++nt) {
        const int cur = nt & 1;
        if (nt < 7) {
            const unsigned short* bpn = cbf2 + ((size_t)(w * 8 + nt + 1) << 12) + (l << 3);
            #pragma unroll
            for (int kt = 0; kt < 8; ++kt)
                bfr[cur ^ 1][kt] = *(const bf16x8*)(bpn + (kt << 9));
        }
        #pragma unroll
        for (int kt = 0; kt < 8; ++kt) {
            acc[0][nt] = __builtin_amdgcn_mfma_f32_16x16x32_bf16(afr[0][kt], bfr[cur][kt], acc[0][nt], 0, 0, 0);
            acc[1][nt] = __builtin_amdgcn_mfma_f32_16x16x32_bf16(afr[1][kt], bfr[cur][kt], acc[1][nt], 0, 0, 0);
        }
    }

    __syncthreads();

    // per-lane argmin per row, merge across 16-lane col group
    #pragma unroll
    for (int mt = 0; mt < 2; ++mt) {
        #pragma unroll
        for (int reg = 0; reg < 4; ++reg) {
            const int row = mt * 16 + g * 4 + reg;
            float v1 = 3.4028235e38f;
            int   i1 = 0x7fffffff;
            #pragma unroll
            for (int nt = 0; nt < 8; ++nt) {
                const int k = w * 128 + nt * 16 + c0;
                const float s = fmaf(-2.0f, acc[mt][nt][reg], cbsq_s[k]);
                if (s < v1 || (s == v1 && k < i1)) { v1 = s; i1 = k; }
            }
            #pragma unroll
            for (int m = 1; m < 16; m <<= 1) {
                float pv1 = __shfl_xor(v1, m, 64);
                int   pi1 = __shfl_xor(i1, m, 64);
                if (pv1 < v1 || (pv1 == v1 && pi1 < i1)) { v1 = pv1; i1 = pi1; }
            }
            if (c0 == 0) {
                red[(w * 32 + row) * 2 + 0] = v1;
                red[(w * 32 + row) * 2 + 1] = __int_as_float(i1);
            }
        }
    }
    __syncthreads();

    if (t < 32) {
        float v1 = red[(0 * 32 + t) * 2 + 0];
        int   i1 = __float_as_int(red[(0 * 32 + t) * 2 + 1]);
        #pragma unroll
        for (int ww = 1; ww < 4; ++ww) {
            float pv1 = red[(ww * 32 + t) * 2 + 0];
            int   pi1 = __float_as_int(red[(ww * 32 + t) * 2 + 1]);
            if (pv1 < v1 || (pv1 == v1 && pi1 < i1)) { v1 = pv1; i1 = pi1; }
        }
        out[IDX_OFF + m0 + t] = (float)i1;   // provisional (final unless refined)
        fv1[t] = v1;
    }
    __syncthreads();

    // candidate scan: every code within TAU of the row min
    #pragma unroll
    for (int mt = 0; mt < 2; ++mt) {
        #pragma unroll
        for (int reg = 0; reg < 4; ++reg) {
            const int row = mt * 16 + g * 4 + reg;
            const float lim = fv1[row] + TAU;
            #pragma unroll
            for (int nt = 0; nt < 8; ++nt) {
                const int k = w * 128 + nt * 16 + c0;
                const float s = fmaf(-2.0f, acc[mt][nt][reg], cbsq_s[k]);
                if (s < lim) {
                    int pos = atomicAdd(&ccnt[row], 1);
                    if (pos < 8) cand[row][pos] = k;
                }
            }
        }
    }
    __syncthreads();

    if (t < 32) {
        const int nc = ccnt[t];
        if (nc > 1) {
            int slot = atomicAdd(wsi + 1, 1);
            if (slot < GL_CAP) {
                int* gl = wsi + WS_GLI + slot * 10;
                gl[0] = m0 + t;
                gl[1] = (nc > 8) ? NC_FULL : nc;
                #pragma unroll
                for (int q = 0; q < 8; ++q)
                    gl[2 + q] = (q < nc && q < 8) ? cand[t][q] : 0;
            }
        }
    }
}

// Exact np-replica on candidate codes only. One block per flagged row. (r6)
__global__ void vq_refine(const float* __restrict__ z,
                          const float* __restrict__ cb,
                          float* __restrict__ ws,
                          float* __restrict__ out) {
    int* wsi = (int*)ws;
    const int cnt = min(wsi[1], GL_CAP);
    const int t   = threadIdx.x;
    const int wid = t >> 6;
    const int l   = t & 63;

    __shared__ __align__(16) float zs[260];
    __shared__ float chres[16];
    __shared__ float zsq_sh;
    __shared__ float wbv[4];
    __shared__ int   wbi[4];

    for (int slot = blockIdx.x; slot < cnt; slot += gridDim.x) {
        __syncthreads();
        const int* gl = wsi + WS_GLI + slot * 10;
        const int n  = gl[0];
        const int nc = gl[1];
        const size_t zb = (size_t)(n >> 12) * 1048576 + (size_t)(n & 4095);
        zs[t] = z[zb + (size_t)t * 4096];
        __syncthreads();

        if (t < 16) {
            const float* a = &zs[(t & 8) * 16];
            const int j = t & 7;
            float r = __fmul_rn(a[j], a[j]);
            #pragma unroll 1
            for (int m = 1; m < 16; ++m)
                r = __fadd_rn(r, __fmul_rn(a[j + 8 * m], a[j + 8 * m]));
            chres[t] = r;
        }
        __syncthreads();
        if (t == 0) {
            float h0 = __fadd_rn(__fadd_rn(__fadd_rn(chres[0], chres[1]), __fadd_rn(chres[2], chres[3])),
                                 __fadd_rn(__fadd_rn(chres[4], chres[5]), __fadd_rn(chres[6], chres[7])));
            float h1 = __fadd_rn(__fadd_rn(__fadd_rn(chres[8], chres[9]), __fadd_rn(chres[10], chres[11])),
                                 __fadd_rn(__fadd_rn(chres[12], chres[13]), __fadd_rn(chres[14], chres[15])));
            zsq_sh = __fadd_rn(h0, h1);
        }
        __syncthreads();
        const float zsq = zsq_sh;
        const float4 zl = *(const float4*)&zs[4 * l];

        float bv = 3.4028235e38f;
        int   bi = 0x7fffffff;
        if (nc != NC_FULL) {
            for (int ci = wid; ci < nc; ci += 4) {
                const int k = gl[2 + ci];
                const float4 e = *(const float4*)(cb + (size_t)k * CDIM + 4 * l);
                double d = (double)e.x * (double)zl.x + (double)e.y * (double)zl.y
                         + (double)e.z * (double)zl.z + (double)e.w * (double)zl.w;
                #pragma unroll
                for (int m = 1; m < 64; m <<= 1)
                    d += __shfl_xor(d, m, 64);
                const float dist = __fsub_rn(__fadd_rn(zsq, ws[WS_CBSQ + k]),
                                             __fmul_rn(2.0f, (float)d));
                if (dist < bv || (dist == bv && k < bi)) { bv = dist; bi = k; }
            }
        } else {
            for (int k = wid; k < KCODES; k += 4) {
                const float4 e = *(const float4*)(cb + (size_t)k * CDIM + 4 * l);
                double d = (double)e.x * (double)zl.x + (double)e.y * (double)zl.y
                         + (double)e.z * (double)zl.z + (double)e.w * (double)zl.w;
                #pragma unroll
                for (int m = 1; m < 64; m <<= 1)
                    d += __shfl_xor(d, m, 64);
                const float dist = __fsub_rn(__fadd_rn(zsq, ws[WS_CBSQ + k]),
                                             __fmul_rn(2.0f, (float)d));
                if (dist < bv || (dist == bv && k < bi)) { bv = dist; bi = k; }
            }
        }
        if (l == 0) { wbv[wid] = bv; wbi[wid] = bi; }
        __syncthreads();
        if (t == 0) {
            float v = wbv[0]; int i = wbi[0];
            #pragma unroll
            for (int ww = 1; ww < 4; ++ww) {
                if (wbv[ww] < v || (wbv[ww] == v && wbi[ww] < i)) { v = wbv[ww]; i = wbi[ww]; }
            }
            out[IDX_OFF + n] = (float)i;
        }
    }
}

// z_q gather + loss: block = 32 consecutive positions x 256 channels.
__launch_bounds__(256, 4)
__global__ void vq_gather(const float* __restrict__ z,
                          const float* __restrict__ cb,
                          float* __restrict__ out,
                          float* __restrict__ ws) {
    __shared__ int   sidx[32];
    __shared__ float lcb[32][257];
    const int t  = threadIdx.x;
    const int n0 = blockIdx.x * 32;
    const int b  = n0 >> 12;
    const int s0 = n0 & 4095;

    if (t < 32) sidx[t] = (int)out[IDX_OFF + n0 + t];
    __syncthreads();

    #pragma unroll 4
    for (int e = t; e < 32 * 256; e += 256) {
        const int r = e >> 8, c = e & 255;
        lcb[r][c] = cb[(size_t)sidx[r] * CDIM + c];
    }
    __syncthreads();

    float acc = 0.0f;
    const int sl = t & 31, cg = t >> 5;
    const size_t base = (size_t)b * 1048576 + (size_t)s0 + sl;
    #pragma unroll 4
    for (int i = 0; i < 32; ++i) {
        const int c = i * 8 + cg;
        const size_t o = base + (size_t)c * 4096;
        float v  = lcb[sl][c];
        float zv = z[o];
        out[o] = v;
        float df = v - zv;
        acc += df * df;
    }

    #pragma unroll
    for (int off = 32; off > 0; off >>= 1)
        acc += __shfl_down(acc, off, 64);
    __shared__ float wsum[4];
    const int lane = t & 63, wid = t >> 6;
    if (lane == 0) wsum[wid] = acc;
    __syncthreads();
    if (t == 0)
        atomicAdd(&ws[0], wsum[0] + wsum[1] + wsum[2] + wsum[3]);
}

__global__ void vq_fin(const float* __restrict__ ws, float* __restrict__ out) {
    if (threadIdx.x == 0)
        out[ZTOT] = 1.25f * ws[0] / (float)ZTOT;
}

extern "C" void kernel_launch(void* const* d_in, const int* in_sizes, int n_in,
                              void* d_out, int out_size, void* d_ws, size_t ws_size,
                              hipStream_t stream) {
    const float* z  = (const float*)d_in[0];
    const float* cb = (const float*)d_in[1];
    float* out = (float*)d_out;
    float* ws  = (float*)d_ws;

    vq_prep<<<1, 512, 0, stream>>>(cb, ws);
    vq_cvt<<<512, 256, 0, stream>>>(cb, ws);
    vq_screen<<<NPOS / 32, 256, 0, stream>>>(z, ws, out);
    vq_refine<<<2048, 256, 0, stream>>>(z, cb, ws, out);
    vq_gather<<<NPOS / 32, 256, 0, stream>>>(z, cb, out, ws);
    vq_fin<<<1, 64, 0, stream>>>(ws, out);
}